// Round 7
// baseline (483.001 us; speedup 1.0000x reference)
//
#include <hip/hip_runtime.h>
#include <math.h>

// Fused morphological opening: erode(10x10 flat, SAME) then dilate(10x10 flat,
// SAME), NHWC fp32 [16,512,512,8]. One kernel; eroded intermediate in LDS.
//
// R6 post-mortem: occupancy is uncorrelated with perf across R1-R6 (38%->103us,
// 43%->162, 60%->176, 64%->350-spill). All pipes idle ~2/3: the serially-
// barriered phase chain clusters every wave into the same pipe. R7 makes the
// overlap EXPLICIT (producer/consumer waves + z-pipelining, 1 block/CU):
//   waves 2-7 (producers): issue next-z tile's global loads -> regs at iter
//     start (HBM latency hides under the whole compute chain), minV-reduce and
//     ds_write into the OTHER LDS buffer at iter end (overlaps P5).
//   waves 0-1 (consumers): minH (P2), maxV (P3), maxH (P4), store (P5) as
//     thread-private in-place streams: one thread owns a whole row (P2/P4) or
//     column (P3); GW reads lead in-place writes by 9 taps -> race-free with
//     NO intra-phase barrier. 4 barriers/tile (was 8).
// Raw s_barrier + explicit lgkmcnt(0) + memory clobbers (NOT __syncthreads,
// which drains vmcnt(0) per wave and would serialize the prefetch).
// Geometry: TH=32 (16 exact bands), RA=41 rows, 50 px staged (S_A=101 f4).
// LDS = 2 x 41*101*16 = 132,512 B (<160 KiB/CU) -> 1 block/CU, 8 waves.
// NZ=8 z-tiles per block; grid (16,16,2) = 512 blocks = exactly 2/CU.
// Boundary semantics (lax.reduce_window SAME): erosion pads input +inf (P1
// stages pinf for OOB rows/cols); dilation pads the *eroded* image -inf
// outside [0,512) (abs-row / abs-px masks, rim blocks only).
// Tripwire: WRITE_SIZE must stay exactly 131072 KB (no scratch spill; R5/R6
// lesson). launch_bounds(512,2) -> VGPR cap 256; expect ~200.

#define W_F4   1024              // 512 px * 2 f4 (8 ch)
#define IMG_F4 (512 * W_F4)
#define TH     32                // output rows per tile (512/32 = 16 bands)
#define TW     32                // output px per tile
#define RA     41                // sA rows = TH + 9
#define CA     100               // staged cols (f4) = (TW + 18) * 2
#define S_A    101               // sA row stride (f4)
#define BUF_F4 (RA * S_A)        // 4141 f4 = 66,256 B per buffer
#define NZ     8                 // z-tiles per block (pipeline depth)

__device__ __forceinline__ float4 f4min(float4 a, float4 b) {
    return make_float4(fminf(a.x,b.x), fminf(a.y,b.y), fminf(a.z,b.z), fminf(a.w,b.w));
}
__device__ __forceinline__ float4 f4max(float4 a, float4 b) {
    return make_float4(fmaxf(a.x,b.x), fmaxf(a.y,b.y), fmaxf(a.z,b.z), fmaxf(a.w,b.w));
}
template<bool MIN>
__device__ __forceinline__ float4 f4op(float4 a, float4 b) {
    return MIN ? f4min(a, b) : f4max(a, b);
}

// Raw barrier: LDS-ordering only. lgkmcnt(0) makes prior ds_writes visible;
// vmcnt is deliberately NOT drained (in-flight prefetch survives). Clobbers
// stop the compiler moving LDS ops across in either direction.
__device__ __forceinline__ void bar_lds() {
    asm volatile("s_waitcnt lgkmcnt(0)" ::: "memory");
    __builtin_amdgcn_s_barrier();
    asm volatile("" ::: "memory");
}

// Gil-Werman run: emit(i, reduce(tap(i)..tap(i+9))) for i in [0,R), 1<=R<=16.
// Reads taps q in [0,R+9). Emit is interleaved: read of tap(9+i) precedes
// emit(i) -> for in-place streams, reads lead writes by 9 (race-free).
template<int R, bool MIN, class TapF, class EmitF>
__device__ __forceinline__ void gw_run(TapF tap, EmitF emit) {
    constexpr int C1 = (R < 8) ? R : 8;
    float4 v8, L[9];
    {
        float4 v[9];
#pragma unroll
        for (int q = 0; q < 9; q++) v[q] = tap(q);
        v8 = v[8];
        L[8] = v[8];
#pragma unroll
        for (int i = 7; i >= 0; i--) L[i] = f4op<MIN>(v[i], L[i + 1]);
    }
    float4 w[8], rr;
#pragma unroll
    for (int i = 0; i < C1; i++) {           // taps 9..8+C1
        float4 tv = tap(9 + i);
        w[i] = tv;
        rr = i ? f4op<MIN>(rr, tv) : tv;
        emit(i, f4op<MIN>(L[i], rr));
    }
    if (R > 8) {
        float4 L2[9];
        L2[8] = w[7];                        // tap 16
#pragma unroll
        for (int i = 7; i >= 1; i--) L2[i] = f4op<MIN>(w[i - 1], L2[i + 1]);
        L2[0] = f4op<MIN>(v8, L2[1]);
        float4 r2;
#pragma unroll
        for (int i = 0; i < R - 8; i++) {    // taps 17..R+8
            float4 tv = tap(17 + i);
            r2 = i ? f4op<MIN>(r2, tv) : tv;
            emit(8 + i, f4op<MIN>(L2[i], r2));
        }
    }
}

// ---- P1 split: load taps into regs (issue-early) / reduce+stage (write-late).
// Task (p, c): p in {0,1}: rows s0=p*16, R=16, 25 taps; p=2: s0=32, R=9, 18 taps.
__device__ __forceinline__ void p1_load(const float4* __restrict__ img,
                                        int h0, int w0, bool yin,
                                        int p, int c, float4* v) {
    const int s0    = (p < 2) ? p * 16 : 32;
    const int NT    = (p < 2) ? 25 : 18;
    const int hbase = h0 - 8 + s0;
    const int colf4 = w0 * 2 - 16 + c;
    const float4 pinf4 = make_float4(INFINITY, INFINITY, INFINITY, INFINITY);
    const bool colok = (colf4 >= 0) & (colf4 < W_F4);
    if (yin && colok) {                      // interior: unmasked column burst
        const float4* col = img + (size_t)hbase * W_F4 + colf4;
#pragma unroll
        for (int q = 0; q < 25; q++)
            if (q < NT) v[q] = col[(size_t)q * W_F4];
    } else {                                 // rim: per-tap mask (+inf pad)
#pragma unroll
        for (int q = 0; q < 25; q++)
            if (q < NT) {
                int h = hbase + q;
                bool ok = colok & (h >= 0) & (h < 512);
                v[q] = ok ? img[(size_t)h * W_F4 + colf4] : pinf4;
            }
    }
}
__device__ __forceinline__ void p1_stage(float4* __restrict__ sbuf,
                                         int p, int c, const float4* v) {
    const int s0 = (p < 2) ? p * 16 : 32;
    if (p < 2) {
        gw_run<16, true>([&](int q) { return v[q]; },
                         [&](int i, float4 o) { sbuf[(s0 + i) * S_A + c] = o; });
    } else {
        gw_run<9, true>([&](int q) { return v[q]; },
                        [&](int i, float4 o) { sbuf[(s0 + i) * S_A + c] = o; });
    }
}

__global__ __launch_bounds__(512, 2) void opening(const float4* __restrict__ in,
                                                  float4* __restrict__ out) {
    __shared__ float4 sA[2 * BUF_F4];        // 132,512 B -> 1 block/CU

    const float4 ninf4 = make_float4(-INFINITY, -INFINITY, -INFINITY, -INFINITY);

    const int t  = threadIdx.x;
    const int h0 = blockIdx.y * TH;
    const int w0 = blockIdx.x * TW;
    const int z0 = blockIdx.z * NZ;
    const bool yin = (h0 >= 8) && (h0 + 41 < 512);        // by in [1,14]
    const bool xin = (w0 >= 8) && (2 * w0 + 83 < W_F4);   // bx in [1,14]

    // producer lanes: waves 2-7; p = run id (wave-uniform), c = staged f4 col
    const int  lp = (t - 128) >> 7;
    const int  lc = (t - 128) & 127;
    const bool wl = (t >= 128) && (lc < CA);

    // ---- prologue: stage tile z0 into buf 0 (latency exposed once/block) ----
    if (wl) {
        float4 v[25];
        p1_load(in + (size_t)z0 * IMG_F4, h0, w0, yin, lp, lc, v);
        p1_stage(sA, lp, lc, v);
    }
    bar_lds();

    for (int k = 0; k < NZ; ++k) {
        float4* cbuf = sA + (size_t)(k & 1) * BUF_F4;
        float4* nbuf = sA + (size_t)((k + 1) & 1) * BUF_F4;

        // ---- A) producers: ISSUE next tile's loads (no wait; in flight
        //         across the raw barriers below) ----
        float4 v[25];
        const bool pf = wl && (k + 1 < NZ);
        if (pf) p1_load(in + (size_t)(z0 + k + 1) * IMG_F4, h0, w0, yin, lp, lc, v);

        // ---- P2: horizontal min, private per (row, c4). 82 tasks ----
        // taps minV px j..j+9 (50 staged px); outputs eroded px 0..40 in place.
        if (t < 2 * RA) {
            float4* row = cbuf + (t >> 1) * S_A + (t & 1);
            gw_run<16, true>([&](int q) { return row[2 * q]; },
                             [&](int i, float4 o) { row[2 * i] = o; });
            gw_run<16, true>([&](int q) { return row[2 * (16 + q)]; },
                             [&](int i, float4 o) { row[2 * (16 + i)] = o; });
            gw_run<9, true>([&](int q) { return row[2 * (32 + q)]; },
                            [&](int i, float4 o) { row[2 * (32 + i)] = o; });
        }
        bar_lds();

        // ---- P3: vertical max, private per column. 82 tasks ----
        // taps eroded rows s=o..o+9 (41 rows); outputs rows 0..31 in place.
        // Tap = -inf when eroded abs row h0-4+s outside [0,512).
        if (t < 82) {
            const int c = t;
            if (yin) {
                gw_run<16, false>([&](int q) { return cbuf[q * S_A + c]; },
                                  [&](int i, float4 o) { cbuf[i * S_A + c] = o; });
                gw_run<16, false>([&](int q) { return cbuf[(16 + q) * S_A + c]; },
                                  [&](int i, float4 o) { cbuf[(16 + i) * S_A + c] = o; });
            } else {
                gw_run<16, false>(
                    [&](int q) { int h = h0 - 4 + q; float4 val = cbuf[q * S_A + c];
                                 return ((h >= 0) & (h < 512)) ? val : ninf4; },
                    [&](int i, float4 o) { cbuf[i * S_A + c] = o; });
                gw_run<16, false>(
                    [&](int q) { int s = 16 + q; int h = h0 - 4 + s;
                                 float4 val = cbuf[s * S_A + c];
                                 return ((h >= 0) & (h < 512)) ? val : ninf4; },
                    [&](int i, float4 o) { cbuf[(16 + i) * S_A + c] = o; });
            }
        }
        bar_lds();

        // ---- P4: horizontal max, private per (row, c4). 64 tasks ----
        // taps eroded px j=x..x+9 (41 px); outputs px 0..31 in place.
        // Tap = -inf when eroded abs px w0-4+j outside [0,512).
        if (t < 2 * TH) {
            float4* row = cbuf + (t >> 1) * S_A + (t & 1);
            if (xin) {
                gw_run<16, false>([&](int q) { return row[2 * q]; },
                                  [&](int i, float4 o) { row[2 * i] = o; });
                gw_run<16, false>([&](int q) { return row[2 * (16 + q)]; },
                                  [&](int i, float4 o) { row[2 * (16 + i)] = o; });
            } else {
                gw_run<16, false>(
                    [&](int q) { int px = w0 - 4 + q; float4 val = row[2 * q];
                                 return ((px >= 0) & (px < 512)) ? val : ninf4; },
                    [&](int i, float4 o) { row[2 * i] = o; });
                gw_run<16, false>(
                    [&](int q) { int j = 16 + q; int px = w0 - 4 + j;
                                 float4 val = row[2 * j];
                                 return ((px >= 0) & (px < 512)) ? val : ninf4; },
                    [&](int i, float4 o) { row[2 * (16 + i)] = o; });
            }
        }
        bar_lds();

        // ---- P5 (consumers): coalesced store, 2048 f4, 16 per thread ----
        if (t < 128) {
            float4* oimg = out + (size_t)(z0 + k) * IMG_F4;
#pragma unroll
            for (int i = 0; i < 16; ++i) {
                int idx = t + i * 128;       // wave = one full 1 KB row chunk
                int r = idx >> 6, c = idx & 63;
                oimg[(size_t)(h0 + r) * W_F4 + (size_t)(w0 * 2) + c] =
                    cbuf[r * S_A + c];
            }
        }
        // ---- producers: wait loads (first vmcnt since issue), reduce, stage
        //      into the other buffer (overlaps P5's global stores) ----
        if (pf) p1_stage(nbuf, lp, lc, v);
        bar_lds();
    }
}

extern "C" void kernel_launch(void* const* d_in, const int* in_sizes, int n_in,
                              void* d_out, int out_size, void* d_ws, size_t ws_size,
                              hipStream_t stream) {
    const float4* in  = (const float4*)d_in[0];
    float4*       out = (float4*)d_out;
    (void)d_ws; (void)ws_size;               // workspace not needed

    dim3 grid(512 / TW, 512 / TH, 16 / NZ);  // 16 x 16 x 2 = 512 blocks = 2/CU
    opening<<<grid, 512, 0, stream>>>(in, out);
}